// Round 1
// baseline (3397.264 us; speedup 1.0000x reference)
//
#include <hip/hip_runtime.h>

#define NVOX 4096   // 16*16*16
#define CDIM 128

// ---------------- conv1: Conv3d(64->128, k=3, p=1) + bias + pos ----------------
__global__ __launch_bounds__(256) void conv1_kernel(
    const float* __restrict__ x,    // [64][4096]
    const float* __restrict__ w,    // [128][64][27]
    const float* __restrict__ b,    // [128]
    const float* __restrict__ pos,  // [128][4096]
    float* __restrict__ out)        // [128][4096]
{
    __shared__ float wlds[64 * 27];
    const int tid = threadIdx.x;
    const int blk = blockIdx.x;     // 0..2047
    const int co  = blk >> 4;       // 16 blocks per output channel
    const int z   = blk & 15;       // z slice (block covers full 16x16 plane)

    for (int i = tid; i < 64 * 27; i += 256) wlds[i] = w[co * 64 * 27 + i];
    __syncthreads();

    const int y  = tid >> 4;
    const int xx = tid & 15;

    float acc = 0.f;
    for (int ci = 0; ci < 64; ++ci) {
        const float* xin = x + ci * NVOX;
        const float* wl  = wlds + ci * 27;
        #pragma unroll
        for (int dz = 0; dz < 3; ++dz) {
            const int zz = z + dz - 1;
            if (zz < 0 || zz > 15) continue;
            #pragma unroll
            for (int dy = 0; dy < 3; ++dy) {
                const int yy = y + dy - 1;
                if (yy < 0 || yy > 15) continue;
                #pragma unroll
                for (int dx = 0; dx < 3; ++dx) {
                    const int xw = xx + dx - 1;
                    if (xw < 0 || xw > 15) continue;
                    acc += wl[(dz * 3 + dy) * 3 + dx] * xin[(zz * 16 + yy) * 16 + xw];
                }
            }
        }
    }
    const int n = (z * 16 + y) * 16 + xx;
    out[co * NVOX + n] = acc + b[co] + pos[co * NVOX + n];
}

// ---------------- proj: q/k/v = lat^T @ W^T + b  ([8][4096][16] layout) ----------------
__global__ __launch_bounds__(256) void proj_kernel(
    const float* __restrict__ lat,  // [128][4096]
    const float* __restrict__ Wq, const float* __restrict__ bq,
    const float* __restrict__ Wk, const float* __restrict__ bk,
    const float* __restrict__ Wv, const float* __restrict__ bv,
    float* __restrict__ q, float* __restrict__ k, float* __restrict__ v)
{
    const int which = blockIdx.z;
    const float* W  = (which == 0) ? Wq : (which == 1) ? Wk : Wv;
    const float* bb = (which == 0) ? bq : (which == 1) ? bk : bv;
    float*       o  = (which == 0) ? q  : (which == 1) ? k  : v;

    const int co = blockIdx.y;               // 0..127
    const int n  = blockIdx.x * 256 + threadIdx.x;

    float acc = bb[co];
    const float* wr = W + co * CDIM;
    #pragma unroll 8
    for (int c = 0; c < CDIM; ++c)
        acc += wr[c] * lat[c * NVOX + n];

    const int h = co >> 4, d = co & 15;
    o[(h * NVOX + n) * 16 + d] = acc;
}

// ---------------- attn: flash-style online softmax, one wave per (head,row) ----------------
__global__ __launch_bounds__(256) void attn_kernel(
    const float* __restrict__ q, const float* __restrict__ k, const float* __restrict__ v,
    const float* __restrict__ latin, float* __restrict__ latout,
    const float* __restrict__ gamma, int layer)
{
    const int wv   = threadIdx.x >> 6;
    const int lane = threadIdx.x & 63;
    const int r    = blockIdx.x * 4 + wv;    // 0..32767
    const int h    = r >> 12;
    const int n    = r & 4095;

    const float* qp = q + (h * NVOX + n) * 16;
    float qv[16];
    #pragma unroll
    for (int d = 0; d < 16; ++d) qv[d] = qp[d];

    float m = -1e30f, l = 0.f;
    float o[16];
    #pragma unroll
    for (int d = 0; d < 16; ++d) o[d] = 0.f;

    for (int i = 0; i < 64; ++i) {
        const int mm = i * 64 + lane;
        const float* kp = k + (h * NVOX + mm) * 16;
        float s = 0.f;
        #pragma unroll
        for (int d = 0; d < 16; ++d) s += qv[d] * kp[d];
        s *= 0.25f;                          // / sqrt(16)

        const float mn    = fmaxf(m, s);
        const float scale = __expf(m - mn);
        const float p     = __expf(s - mn);
        l = l * scale + p;
        const float* vp = v + (h * NVOX + mm) * 16;
        #pragma unroll
        for (int d = 0; d < 16; ++d) o[d] = o[d] * scale + p * vp[d];
        m = mn;
    }

    // butterfly merge of (m, l, o[16]) across 64 lanes
    #pragma unroll
    for (int st = 1; st < 64; st <<= 1) {
        const float om = __shfl_xor(m, st, 64);
        const float ol = __shfl_xor(l, st, 64);
        const float mn = fmaxf(m, om);
        const float a  = __expf(m  - mn);
        const float bb = __expf(om - mn);
        l = l * a + ol * bb;
        #pragma unroll
        for (int d = 0; d < 16; ++d) {
            const float oo = __shfl_xor(o[d], st, 64);
            o[d] = o[d] * a + oo * bb;
        }
        m = mn;
    }

    const float gv  = gamma[layer];
    const float inv = 1.f / l;
    #pragma unroll
    for (int d = 0; d < 16; ++d) {
        if (lane == d) {
            const int c = h * 16 + d;
            latout[c * NVOX + n] = gv * (o[d] * inv) + latin[c * NVOX + n];
        }
    }
}

// ---------------- conv2: ConvTranspose3d(128->128,k=3,s=1,p=1) as conv with flipped/transposed W ----------------
__global__ __launch_bounds__(256) void conv2_kernel(
    const float* __restrict__ lat,  // [128][4096]
    const float* __restrict__ w,    // out_w: [128 in][128 out][27]
    const float* __restrict__ b,    // [128]
    float* __restrict__ out)        // [128][4096]
{
    __shared__ float wlds[128 * 27];
    const int tid = threadIdx.x;
    const int blk = blockIdx.x;
    const int co  = blk >> 4;
    const int z   = blk & 15;

    for (int i = tid; i < 128 * 27; i += 256) {
        const int ci = i / 27, t = i % 27;
        // w_eq[co][ci][t] = out_w[ci][co][26 - t]
        wlds[i] = w[(ci * 128 + co) * 27 + (26 - t)];
    }
    __syncthreads();

    const int y  = tid >> 4;
    const int xx = tid & 15;

    float acc = 0.f;
    for (int ci = 0; ci < 128; ++ci) {
        const float* xin = lat + ci * NVOX;
        const float* wl  = wlds + ci * 27;
        #pragma unroll
        for (int dz = 0; dz < 3; ++dz) {
            const int zz = z + dz - 1;
            if (zz < 0 || zz > 15) continue;
            #pragma unroll
            for (int dy = 0; dy < 3; ++dy) {
                const int yy = y + dy - 1;
                if (yy < 0 || yy > 15) continue;
                #pragma unroll
                for (int dx = 0; dx < 3; ++dx) {
                    const int xw = xx + dx - 1;
                    if (xw < 0 || xw > 15) continue;
                    acc += wl[(dz * 3 + dy) * 3 + dx] * xin[(zz * 16 + yy) * 16 + xw];
                }
            }
        }
    }
    const int n = (z * 16 + y) * 16 + xx;
    out[co * NVOX + n] = acc + b[co];
}

extern "C" void kernel_launch(void* const* d_in, const int* in_sizes, int n_in,
                              void* d_out, int out_size, void* d_ws, size_t ws_size,
                              hipStream_t stream) {
    const float* x     = (const float*)d_in[0];
    const float* lw    = (const float*)d_in[1];
    const float* lb    = (const float*)d_in[2];
    const float* pos   = (const float*)d_in[3];
    const float* qw    = (const float*)d_in[4];
    const float* qb    = (const float*)d_in[5];
    const float* kw    = (const float*)d_in[6];
    const float* kb    = (const float*)d_in[7];
    const float* vw    = (const float*)d_in[8];
    const float* vb    = (const float*)d_in[9];
    const float* gamma = (const float*)d_in[10];
    const float* ow    = (const float*)d_in[11];
    const float* ob    = (const float*)d_in[12];

    float* ws   = (float*)d_ws;
    float* latA = ws;
    float* latB = ws + 1 * 524288;
    float* q    = ws + 2 * 524288;
    float* k    = ws + 3 * 524288;
    float* v    = ws + 4 * 524288;

    conv1_kernel<<<2048, 256, 0, stream>>>(x, lw, lb, pos, latA);

    float* cur = latA;
    float* nxt = latB;
    for (int i = 0; i < 3; ++i) {
        proj_kernel<<<dim3(16, 128, 3), 256, 0, stream>>>(
            cur, qw + i * 16384, qb + i * 128, kw + i * 16384, kb + i * 128,
            vw + i * 16384, vb + i * 128, q, k, v);
        attn_kernel<<<8192, 256, 0, stream>>>(q, k, v, cur, nxt, gamma, i);
        float* t = cur; cur = nxt; nxt = t;
    }

    conv2_kernel<<<2048, 256, 0, stream>>>(cur, ow, ob, (float*)d_out);
}

// Round 3
// 857.232 us; speedup vs baseline: 3.9631x; 3.9631x over previous
//
#include <hip/hip_runtime.h>
#include <hip/hip_bf16.h>

#define NVOX 4096   // 16*16*16
#define CDIM 128

typedef __attribute__((ext_vector_type(8))) short bf16x8;
typedef __attribute__((ext_vector_type(4))) float f32x4;

static __device__ __forceinline__ short f2bf(float f) {
    __hip_bfloat16 h = __float2bfloat16(f);
    union { __hip_bfloat16 h; short s; } u; u.h = h; return u.s;
}

static __device__ __forceinline__ float fexp2(float x) {
    return __builtin_amdgcn_exp2f(x);
}

// ---------------- conv1: Conv3d(64->128, k=3, p=1) + bias + pos ----------------
__global__ __launch_bounds__(256) void conv1_kernel(
    const float* __restrict__ x,    // [64][4096]
    const float* __restrict__ w,    // [128][64][27]
    const float* __restrict__ b,    // [128]
    const float* __restrict__ pos,  // [128][4096]
    float* __restrict__ out)        // [128][4096]
{
    __shared__ float wlds[64 * 27];
    const int tid = threadIdx.x;
    const int blk = blockIdx.x;     // 0..2047
    const int co  = blk >> 4;
    const int z   = blk & 15;

    for (int i = tid; i < 64 * 27; i += 256) wlds[i] = w[co * 64 * 27 + i];
    __syncthreads();

    const int y  = tid >> 4;
    const int xx = tid & 15;

    float acc = 0.f;
    for (int ci = 0; ci < 64; ++ci) {
        const float* xin = x + ci * NVOX;
        const float* wl  = wlds + ci * 27;
        #pragma unroll
        for (int dz = 0; dz < 3; ++dz) {
            const int zz = z + dz - 1;
            if (zz < 0 || zz > 15) continue;
            #pragma unroll
            for (int dy = 0; dy < 3; ++dy) {
                const int yy = y + dy - 1;
                if (yy < 0 || yy > 15) continue;
                #pragma unroll
                for (int dx = 0; dx < 3; ++dx) {
                    const int xw = xx + dx - 1;
                    if (xw < 0 || xw > 15) continue;
                    acc += wl[(dz * 3 + dy) * 3 + dx] * xin[(zz * 16 + yy) * 16 + xw];
                }
            }
        }
    }
    const int n = (z * 16 + y) * 16 + xx;
    out[co * NVOX + n] = acc + b[co] + pos[co * NVOX + n];
}

// ---------------- proj: q/k/v projections, bf16 outputs in MFMA-friendly layouts ----------------
__global__ __launch_bounds__(256) void proj_kernel(
    const float* __restrict__ lat,  // [128][4096]
    const float* __restrict__ Wq, const float* __restrict__ bq,
    const float* __restrict__ Wk, const float* __restrict__ bk,
    const float* __restrict__ Wv, const float* __restrict__ bv,
    short* __restrict__ qB, short* __restrict__ kB, short* __restrict__ vT)
{
    const int which = blockIdx.z;
    const float* W  = (which == 0) ? Wq : (which == 1) ? Wk : Wv;
    const float* bb = (which == 0) ? bq : (which == 1) ? bk : bv;

    const int n   = blockIdx.x * 256 + threadIdx.x;
    const int co0 = blockIdx.y * 8;

    float acc[8];
    #pragma unroll
    for (int j = 0; j < 8; ++j) acc[j] = bb[co0 + j];

    for (int c = 0; c < CDIM; ++c) {
        const float lv = lat[c * NVOX + n];
        #pragma unroll
        for (int j = 0; j < 8; ++j)
            acc[j] += W[(co0 + j) * CDIM + c] * lv;
    }

    if (which == 0) {
        const float s = 0.25f * 1.4426950408889634f;   // 1/sqrt(16) * log2(e)
        #pragma unroll
        for (int j = 0; j < 8; ++j) {
            const int co = co0 + j, h = co >> 4, d = co & 15;
            qB[((h << 12) + n) * 16 + d] = f2bf(acc[j] * s);
        }
    } else if (which == 1) {
        #pragma unroll
        for (int j = 0; j < 8; ++j) {
            const int co = co0 + j, h = co >> 4, d = co & 15;
            kB[((h << 12) + n) * 16 + d] = f2bf(acc[j]);
        }
    } else {
        #pragma unroll
        for (int j = 0; j < 8; ++j)
            vT[(co0 + j) * NVOX + n] = f2bf(acc[j]);
    }
}

// ---------------- attn: MFMA flash attention ----------------
// Per wave: one 16-row q-tile, half the k-range (2048 keys). Computes
// S^T = mfma(K_tile, Q^T): lane holds S[q=lane&15][k=kc+4*(lane>>4)+r].
// Softmax state (m,l) lane-local per q-column; P stays in-register and feeds
// O^T = mfma(V^T, P^T), accumulating O^T[d=4*lg+r][q=lq]. Two k-half waves
// merge via LDS.
__global__ __launch_bounds__(256) void attn_kernel(
    const short* __restrict__ qB, const short* __restrict__ kB, const short* __restrict__ vT,
    const float* __restrict__ latin, float* __restrict__ latout,
    const float* __restrict__ gamma, int layer)
{
    __shared__ float lm[2][16], ll[2][16], lo[2][16][17];

    const int w    = threadIdx.x >> 6;
    const int lane = threadIdx.x & 63;
    const int lg   = lane >> 4;
    const int lq   = lane & 15;
    const int pair = w >> 1;
    const int half = w & 1;

    const int qtile = blockIdx.x * 2 + pair;   // 0..2047
    const int h     = qtile >> 8;
    const int qbase = (qtile & 255) << 4;

    // Q fragment (B operand): Q[qbase+lq][4*lg+j], j=0..3; upper K-half zero
    const short4 qs = *reinterpret_cast<const short4*>(
        qB + ((h << 12) + qbase + lq) * 16 + (lg << 2));
    const bf16x8 qf = {qs.x, qs.y, qs.z, qs.w, 0, 0, 0, 0};

    const short* kh = kB + ((size_t)(h << 12)) * 16;
    const short* vrow = vT + ((h << 4) + lq) * NVOX;

    float m = -1e30f, lsum = 0.f;
    f32x4 acc = {0.f, 0.f, 0.f, 0.f};

    int kc = half * 2048;
    for (int it = 0; it < 64; ++it, kc += 32) {
        const short4 k0 = *reinterpret_cast<const short4*>(kh + (kc + lq) * 16 + (lg << 2));
        const short4 k1 = *reinterpret_cast<const short4*>(kh + (kc + 16 + lq) * 16 + (lg << 2));
        const bf16x8 kf0 = {k0.x, k0.y, k0.z, k0.w, 0, 0, 0, 0};
        const bf16x8 kf1 = {k1.x, k1.y, k1.z, k1.w, 0, 0, 0, 0};

        const f32x4 s0 = __builtin_amdgcn_mfma_f32_16x16x32_bf16(kf0, qf, (f32x4){0.f,0.f,0.f,0.f}, 0, 0, 0);
        const f32x4 s1 = __builtin_amdgcn_mfma_f32_16x16x32_bf16(kf1, qf, (f32x4){0.f,0.f,0.f,0.f}, 0, 0, 0);

        float tmax = fmaxf(fmaxf(fmaxf(s0[0], s0[1]), fmaxf(s0[2], s0[3])),
                           fmaxf(fmaxf(s1[0], s1[1]), fmaxf(s1[2], s1[3])));
        tmax = fmaxf(tmax, __shfl_xor(tmax, 16));
        tmax = fmaxf(tmax, __shfl_xor(tmax, 32));

        const float mn = fmaxf(m, tmax);
        const float sc = fexp2(m - mn);

        const float p0 = fexp2(s0[0] - mn);
        const float p1 = fexp2(s0[1] - mn);
        const float p2 = fexp2(s0[2] - mn);
        const float p3 = fexp2(s0[3] - mn);
        const float p4 = fexp2(s1[0] - mn);
        const float p5 = fexp2(s1[1] - mn);
        const float p6 = fexp2(s1[2] - mn);
        const float p7 = fexp2(s1[3] - mn);

        float psum = ((p0 + p1) + (p2 + p3)) + ((p4 + p5) + (p6 + p7));
        psum += __shfl_xor(psum, 16);
        psum += __shfl_xor(psum, 32);
        lsum = lsum * sc + psum;
        m = mn;

        acc[0] *= sc; acc[1] *= sc; acc[2] *= sc; acc[3] *= sc;

        const bf16x8 pf = {f2bf(p0), f2bf(p1), f2bf(p2), f2bf(p3),
                           f2bf(p4), f2bf(p5), f2bf(p6), f2bf(p7)};

        const short4 v0 = *reinterpret_cast<const short4*>(vrow + kc + (lg << 2));
        const short4 v1 = *reinterpret_cast<const short4*>(vrow + kc + 16 + (lg << 2));
        const bf16x8 vf = {v0.x, v0.y, v0.z, v0.w, v1.x, v1.y, v1.z, v1.w};

        acc = __builtin_amdgcn_mfma_f32_16x16x32_bf16(vf, pf, acc, 0, 0, 0);
    }

    if (half == 1) {
        if (lg == 0) { lm[pair][lq] = m; ll[pair][lq] = lsum; }
        #pragma unroll
        for (int r = 0; r < 4; ++r) lo[pair][(lg << 2) + r][lq] = acc[r];
    }
    __syncthreads();
    if (half == 0) {
        const float m1 = lm[pair][lq], l1 = ll[pair][lq];
        const float mn = fmaxf(m, m1);
        const float a  = fexp2(m - mn);
        const float b2 = fexp2(m1 - mn);
        const float inv = 1.f / (lsum * a + l1 * b2);
        const float gv  = gamma[layer];
        const int n = qbase + lq;
        #pragma unroll
        for (int r = 0; r < 4; ++r) {
            const float o = (acc[r] * a + lo[pair][(lg << 2) + r][lq] * b2) * inv;
            const int c = (h << 4) + (lg << 2) + r;
            latout[c * NVOX + n] = gv * o + latin[c * NVOX + n];
        }
    }
}

// ---------------- conv2: ConvTranspose3d(128->128,k=3,s=1,p=1) ----------------
__global__ __launch_bounds__(256) void conv2_kernel(
    const float* __restrict__ lat,  // [128][4096]
    const float* __restrict__ w,    // out_w: [128 in][128 out][27]
    const float* __restrict__ b,    // [128]
    float* __restrict__ out)        // [128][4096]
{
    __shared__ float wlds[128 * 27];
    const int tid = threadIdx.x;
    const int blk = blockIdx.x;
    const int co  = blk >> 4;
    const int z   = blk & 15;

    for (int i = tid; i < 128 * 27; i += 256) {
        const int ci = i / 27, t = i % 27;
        wlds[i] = w[(ci * 128 + co) * 27 + (26 - t)];
    }
    __syncthreads();

    const int y  = tid >> 4;
    const int xx = tid & 15;

    float acc = 0.f;
    for (int ci = 0; ci < 128; ++ci) {
        const float* xin = lat + ci * NVOX;
        const float* wl  = wlds + ci * 27;
        #pragma unroll
        for (int dz = 0; dz < 3; ++dz) {
            const int zz = z + dz - 1;
            if (zz < 0 || zz > 15) continue;
            #pragma unroll
            for (int dy = 0; dy < 3; ++dy) {
                const int yy = y + dy - 1;
                if (yy < 0 || yy > 15) continue;
                #pragma unroll
                for (int dx = 0; dx < 3; ++dx) {
                    const int xw = xx + dx - 1;
                    if (xw < 0 || xw > 15) continue;
                    acc += wl[(dz * 3 + dy) * 3 + dx] * xin[(zz * 16 + yy) * 16 + xw];
                }
            }
        }
    }
    const int n = (z * 16 + y) * 16 + xx;
    out[co * NVOX + n] = acc + b[co];
}

extern "C" void kernel_launch(void* const* d_in, const int* in_sizes, int n_in,
                              void* d_out, int out_size, void* d_ws, size_t ws_size,
                              hipStream_t stream) {
    const float* x     = (const float*)d_in[0];
    const float* lw    = (const float*)d_in[1];
    const float* lb    = (const float*)d_in[2];
    const float* pos   = (const float*)d_in[3];
    const float* qw    = (const float*)d_in[4];
    const float* qb    = (const float*)d_in[5];
    const float* kw    = (const float*)d_in[6];
    const float* kb    = (const float*)d_in[7];
    const float* vw    = (const float*)d_in[8];
    const float* vb    = (const float*)d_in[9];
    const float* gamma = (const float*)d_in[10];
    const float* ow    = (const float*)d_in[11];
    const float* ob    = (const float*)d_in[12];

    float* latA = (float*)d_ws;
    float* latB = latA + 524288;
    short* qB   = (short*)(latB + 524288);
    short* kB   = qB + 524288;
    short* vT   = kB + 524288;

    conv1_kernel<<<2048, 256, 0, stream>>>(x, lw, lb, pos, latA);

    float* cur = latA;
    float* nxt = latB;
    for (int i = 0; i < 3; ++i) {
        proj_kernel<<<dim3(16, 16, 3), 256, 0, stream>>>(
            cur, qw + i * 16384, qb + i * 128, kw + i * 16384, kb + i * 128,
            vw + i * 16384, vb + i * 128, qB, kB, vT);
        attn_kernel<<<1024, 256, 0, stream>>>(qB, kB, vT, cur, nxt, gamma, i);
        float* t = cur; cur = nxt; nxt = t;
    }

    conv2_kernel<<<2048, 256, 0, stream>>>(cur, ow, ob, (float*)d_out);
}

// Round 4
// 341.665 us; speedup vs baseline: 9.9433x; 2.5090x over previous
//
#include <hip/hip_runtime.h>
#include <hip/hip_bf16.h>

#define NVOX 4096   // 16*16*16
#define CDIM 128

typedef __attribute__((ext_vector_type(8))) short bf16x8;
typedef __attribute__((ext_vector_type(4))) float f32x4;

static __device__ __forceinline__ short f2bf(float f) {
    __hip_bfloat16 h = __float2bfloat16(f);
    union { __hip_bfloat16 h; short s; } u; u.h = h; return u.s;
}
static __device__ __forceinline__ float fexp2(float x) {
    return __builtin_amdgcn_exp2f(x);
}
// MFMA K-fragment permutation: packed position p <- channel ci
__device__ __forceinline__ int permpos(int ci) {
    return (((ci >> 2) & 3) << 3) + (ci & 3) + ((ci & 16) >> 2) + ((ci >> 5) << 5);
}
__device__ __forceinline__ int invp(int p) {
    const int c = p >> 5, r = p & 31, g = (r >> 3) & 3, j = r & 7;
    return (c << 5) + (j < 4 ? (g << 2) + j : 16 + (g << 2) + (j - 4));
}

// ---------------- prep kernels ----------------
// x [64][4096] f32 -> xpad [5832][64] bf16 (perm'd channels, zero borders)
__global__ __launch_bounds__(256) void pack_x(const float* __restrict__ x, short* __restrict__ xp) {
    const int e = blockIdx.x * 256 + threadIdx.x;
    if (e >= 5832 * 64) return;
    const int vp = e >> 6, p = e & 63;
    const int z = vp / 324, rem = vp - z * 324, y = rem / 18, xx = rem % 18;
    short val = 0;
    if (z >= 1 && z <= 16 && y >= 1 && y <= 16 && xx >= 1 && xx <= 16) {
        const int n = ((z - 1) * 16 + (y - 1)) * 16 + (xx - 1);
        val = f2bf(x[invp(p) * NVOX + n]);
    }
    xp[e] = val;
}

// lateral_w [128][64][27] -> wbf1 [27][128][64perm]
__global__ __launch_bounds__(256) void pack_w1(const float* __restrict__ lw, short* __restrict__ wb) {
    const int e = blockIdx.x * 256 + threadIdx.x;
    if (e >= 27 * 128 * 64) return;
    const int t = e >> 13, co = (e >> 6) & 127, p = e & 63;
    wb[e] = f2bf(lw[(co * 64 + invp(p)) * 27 + t]);
}

// qw/kw/vw [3][128][128] -> wqkv [3][3][128][128perm]
__global__ __launch_bounds__(256) void pack_wqkv(const float* __restrict__ qw, const float* __restrict__ kw,
                                                 const float* __restrict__ vw, short* __restrict__ wb) {
    const int e = blockIdx.x * 256 + threadIdx.x;
    if (e >= 3 * 3 * 128 * 128) return;
    const int l = e / 49152, r = e - l * 49152;
    const int m = r >> 14, co = (r >> 7) & 127, p = r & 127;
    const float* W = (m == 0 ? qw : m == 1 ? kw : vw) + l * 16384;
    wb[e] = f2bf(W[co * 128 + invp(p)]);
}

// out_w [128ci][128co][27] -> wbf2 [27][128co][128perm] (flip+transpose)
__global__ __launch_bounds__(256) void pack_w2(const float* __restrict__ ow, short* __restrict__ wb) {
    const int e = blockIdx.x * 256 + threadIdx.x;
    if (e >= 27 * 128 * 128) return;
    const int t = e >> 14, co = (e >> 7) & 127, p = e & 127;
    wb[e] = f2bf(ow[(invp(p) * 128 + co) * 27 + (26 - t)]);
}

// latbf [4096][128perm] -> xpad2 [5832][128perm] (spatial pad, 16B copies)
__global__ __launch_bounds__(256) void pad2_kernel(const short* __restrict__ latbf, short* __restrict__ xp) {
    const int e = blockIdx.x * 256 + threadIdx.x;
    if (e >= 5832 * 16) return;
    const int vp = e >> 4, c8 = e & 15;
    const int z = vp / 324, rem = vp - z * 324, y = rem / 18, xx = rem % 18;
    int4 val = {0, 0, 0, 0};
    if (z >= 1 && z <= 16 && y >= 1 && y <= 16 && xx >= 1 && xx <= 16) {
        const int n = ((z - 1) * 16 + (y - 1)) * 16 + (xx - 1);
        val = *reinterpret_cast<const int4*>(latbf + n * 128 + c8 * 8);
    }
    *reinterpret_cast<int4*>(xp + vp * 128 + c8 * 8) = val;
}

// ---------------- conv1: MFMA over 27 taps, K=64 ----------------
__global__ __launch_bounds__(256) void conv1_mfma(
    const short* __restrict__ xp,   // [5832][64perm]
    const short* __restrict__ wb,   // [27][128][64perm]
    const float* __restrict__ bias, const float* __restrict__ pos,
    float* __restrict__ lat, short* __restrict__ latbf)
{
    __shared__ float lo[2][16][17];
    const int wid = threadIdx.x >> 6, lane = threadIdx.x & 63;
    const int lg = lane >> 4, lq = lane & 15;
    const int cot = blockIdx.x >> 7, rp = blockIdx.x & 127;
    const int row = rp * 2 + (wid >> 1);   // 0..255 (z,y) row
    const int half = wid & 1;
    const int z = row >> 4, y = row & 15;
    const int co0 = cot * 16;

    const short* wbase = wb + (co0 + lq) * 64 + lg * 8;
    const short* xbase = xp + lq * 64 + lg * 8;

    f32x4 acc = {0.f, 0.f, 0.f, 0.f};
    const int t0 = half ? 14 : 0, t1 = half ? 27 : 14;
    for (int t = t0; t < t1; ++t) {
        const int dz = t / 9, r9 = t - dz * 9, dy = r9 / 3, dx = r9 - dy * 3;
        const int vp = ((z + dz) * 18 + (y + dy)) * 18 + dx;
        const short* wt = wbase + t * 8192;
        const short* xt = xbase + vp * 64;
        #pragma unroll
        for (int c = 0; c < 2; ++c) {
            const bf16x8 a = *reinterpret_cast<const bf16x8*>(wt + c * 32);
            const bf16x8 b = *reinterpret_cast<const bf16x8*>(xt + c * 32);
            acc = __builtin_amdgcn_mfma_f32_16x16x32_bf16(a, b, acc, 0, 0, 0);
        }
    }
    if (half) {
        #pragma unroll
        for (int r = 0; r < 4; ++r) lo[wid >> 1][lg * 4 + r][lq] = acc[r];
    }
    __syncthreads();
    if (!half) {
        const int n = row * 16 + lq;
        short4 s4;
        #pragma unroll
        for (int r = 0; r < 4; ++r) {
            const int co = co0 + lg * 4 + r;
            const float v = acc[r] + lo[wid >> 1][lg * 4 + r][lq] + bias[co] + pos[co * NVOX + n];
            lat[co * NVOX + n] = v;
            ((short*)&s4)[r] = f2bf(v);
        }
        const int pb = permpos(co0 + lg * 4);
        *reinterpret_cast<short4*>(latbf + n * 128 + pb) = s4;
    }
}

// ---------------- proj: 3x GEMM 128x4096x128, MFMA ----------------
__global__ __launch_bounds__(256) void proj_mfma(
    const short* __restrict__ latbf,     // [4096][128perm]
    const short* __restrict__ wl,        // [3][128][128perm] (this layer)
    const float* __restrict__ bq, const float* __restrict__ bk, const float* __restrict__ bv,
    short* __restrict__ qB, short* __restrict__ kB, short* __restrict__ vT)
{
    const int m = blockIdx.z;
    const int wid = threadIdx.x >> 6, lane = threadIdx.x & 63;
    const int lg = lane >> 4, lq = lane & 15;
    const int co0 = blockIdx.y * 16;
    const int row = blockIdx.x * 4 + wid;
    const int n = row * 16 + lq;

    const short* A = wl + m * 16384 + (co0 + lq) * 128 + lg * 8;
    const short* B = latbf + n * 128 + lg * 8;

    f32x4 acc = {0.f, 0.f, 0.f, 0.f};
    #pragma unroll
    for (int c = 0; c < 4; ++c) {
        const bf16x8 a = *reinterpret_cast<const bf16x8*>(A + c * 32);
        const bf16x8 b = *reinterpret_cast<const bf16x8*>(B + c * 32);
        acc = __builtin_amdgcn_mfma_f32_16x16x32_bf16(a, b, acc, 0, 0, 0);
    }

    const float* bias = (m == 0) ? bq : (m == 1) ? bk : bv;
    if (m == 2) {
        #pragma unroll
        for (int r = 0; r < 4; ++r) {
            const int co = co0 + lg * 4 + r;
            vT[co * NVOX + n] = f2bf(acc[r] + bias[co]);
        }
    } else {
        const float S = (m == 0) ? 0.25f * 1.4426950408889634f : 1.f;
        short4 s4;
        #pragma unroll
        for (int r = 0; r < 4; ++r) {
            const int co = co0 + lg * 4 + r;
            ((short*)&s4)[r] = f2bf((acc[r] + bias[co]) * S);
        }
        const int h = co0 >> 4;
        short* dst = (m == 0) ? qB : kB;
        *reinterpret_cast<short4*>(dst + ((h << 12) + n) * 16 + lg * 4) = s4;
    }
}

// ---------------- attn: MFMA flash attention (as r3) + packed bf16 lat out ----------------
__global__ __launch_bounds__(256) void attn_kernel(
    const short* __restrict__ qB, const short* __restrict__ kB, const short* __restrict__ vT,
    const float* __restrict__ latin, float* __restrict__ latout, short* __restrict__ latbf,
    const float* __restrict__ gamma, int layer)
{
    __shared__ float lm[2][16], ll[2][16], lo[2][16][17];

    const int w    = threadIdx.x >> 6;
    const int lane = threadIdx.x & 63;
    const int lg   = lane >> 4;
    const int lq   = lane & 15;
    const int pair = w >> 1;
    const int half = w & 1;

    const int qtile = blockIdx.x * 2 + pair;
    const int h     = qtile >> 8;
    const int qbase = (qtile & 255) << 4;

    const short4 qs = *reinterpret_cast<const short4*>(
        qB + ((h << 12) + qbase + lq) * 16 + (lg << 2));
    const bf16x8 qf = {qs.x, qs.y, qs.z, qs.w, 0, 0, 0, 0};

    const short* kh = kB + ((size_t)(h << 12)) * 16;
    const short* vrow = vT + ((h << 4) + lq) * NVOX;

    float m = -1e30f, lsum = 0.f;
    f32x4 acc = {0.f, 0.f, 0.f, 0.f};

    int kc = half * 2048;
    for (int it = 0; it < 64; ++it, kc += 32) {
        const short4 k0 = *reinterpret_cast<const short4*>(kh + (kc + lq) * 16 + (lg << 2));
        const short4 k1 = *reinterpret_cast<const short4*>(kh + (kc + 16 + lq) * 16 + (lg << 2));
        const bf16x8 kf0 = {k0.x, k0.y, k0.z, k0.w, 0, 0, 0, 0};
        const bf16x8 kf1 = {k1.x, k1.y, k1.z, k1.w, 0, 0, 0, 0};

        const f32x4 s0 = __builtin_amdgcn_mfma_f32_16x16x32_bf16(kf0, qf, (f32x4){0.f,0.f,0.f,0.f}, 0, 0, 0);
        const f32x4 s1 = __builtin_amdgcn_mfma_f32_16x16x32_bf16(kf1, qf, (f32x4){0.f,0.f,0.f,0.f}, 0, 0, 0);

        float tmax = fmaxf(fmaxf(fmaxf(s0[0], s0[1]), fmaxf(s0[2], s0[3])),
                           fmaxf(fmaxf(s1[0], s1[1]), fmaxf(s1[2], s1[3])));
        tmax = fmaxf(tmax, __shfl_xor(tmax, 16));
        tmax = fmaxf(tmax, __shfl_xor(tmax, 32));

        const float mn = fmaxf(m, tmax);
        const float sc = fexp2(m - mn);

        const float p0 = fexp2(s0[0] - mn);
        const float p1 = fexp2(s0[1] - mn);
        const float p2 = fexp2(s0[2] - mn);
        const float p3 = fexp2(s0[3] - mn);
        const float p4 = fexp2(s1[0] - mn);
        const float p5 = fexp2(s1[1] - mn);
        const float p6 = fexp2(s1[2] - mn);
        const float p7 = fexp2(s1[3] - mn);

        float psum = ((p0 + p1) + (p2 + p3)) + ((p4 + p5) + (p6 + p7));
        psum += __shfl_xor(psum, 16);
        psum += __shfl_xor(psum, 32);
        lsum = lsum * sc + psum;
        m = mn;

        acc[0] *= sc; acc[1] *= sc; acc[2] *= sc; acc[3] *= sc;

        const bf16x8 pf = {f2bf(p0), f2bf(p1), f2bf(p2), f2bf(p3),
                           f2bf(p4), f2bf(p5), f2bf(p6), f2bf(p7)};

        const short4 v0 = *reinterpret_cast<const short4*>(vrow + kc + (lg << 2));
        const short4 v1 = *reinterpret_cast<const short4*>(vrow + kc + 16 + (lg << 2));
        const bf16x8 vf = {v0.x, v0.y, v0.z, v0.w, v1.x, v1.y, v1.z, v1.w};

        acc = __builtin_amdgcn_mfma_f32_16x16x32_bf16(vf, pf, acc, 0, 0, 0);
    }

    if (half == 1) {
        if (lg == 0) { lm[pair][lq] = m; ll[pair][lq] = lsum; }
        #pragma unroll
        for (int r = 0; r < 4; ++r) lo[pair][(lg << 2) + r][lq] = acc[r];
    }
    __syncthreads();
    if (half == 0) {
        const float m1 = lm[pair][lq], l1 = ll[pair][lq];
        const float mn = fmaxf(m, m1);
        const float a  = fexp2(m - mn);
        const float b2 = fexp2(m1 - mn);
        const float inv = 1.f / (lsum * a + l1 * b2);
        const float gv  = gamma[layer];
        const int n = qbase + lq;
        short4 s4;
        #pragma unroll
        for (int r = 0; r < 4; ++r) {
            const float o = (acc[r] * a + lo[pair][(lg << 2) + r][lq] * b2) * inv;
            const int c = (h << 4) + (lg << 2) + r;
            const float v = gv * o + latin[c * NVOX + n];
            latout[c * NVOX + n] = v;
            ((short*)&s4)[r] = f2bf(v);
        }
        const int pb = permpos((h << 4) + (lg << 2));
        *reinterpret_cast<short4*>(latbf + n * 128 + pb) = s4;
    }
}

// ---------------- conv2: MFMA over 27 taps, K=128 ----------------
__global__ __launch_bounds__(256) void conv2_mfma(
    const short* __restrict__ xp,   // [5832][128perm]
    const short* __restrict__ wb,   // [27][128][128perm]
    const float* __restrict__ bias,
    float* __restrict__ out)
{
    __shared__ float lo[2][16][17];
    const int wid = threadIdx.x >> 6, lane = threadIdx.x & 63;
    const int lg = lane >> 4, lq = lane & 15;
    const int cot = blockIdx.x >> 7, rp = blockIdx.x & 127;
    const int row = rp * 2 + (wid >> 1);
    const int half = wid & 1;
    const int z = row >> 4, y = row & 15;
    const int co0 = cot * 16;

    const short* wbase = wb + (co0 + lq) * 128 + lg * 8;
    const short* xbase = xp + lq * 128 + lg * 8;

    f32x4 acc = {0.f, 0.f, 0.f, 0.f};
    const int t0 = half ? 14 : 0, t1 = half ? 27 : 14;
    for (int t = t0; t < t1; ++t) {
        const int dz = t / 9, r9 = t - dz * 9, dy = r9 / 3, dx = r9 - dy * 3;
        const int vp = ((z + dz) * 18 + (y + dy)) * 18 + dx;
        const short* wt = wbase + t * 16384;
        const short* xt = xbase + vp * 128;
        #pragma unroll
        for (int c = 0; c < 4; ++c) {
            const bf16x8 a = *reinterpret_cast<const bf16x8*>(wt + c * 32);
            const bf16x8 b = *reinterpret_cast<const bf16x8*>(xt + c * 32);
            acc = __builtin_amdgcn_mfma_f32_16x16x32_bf16(a, b, acc, 0, 0, 0);
        }
    }
    if (half) {
        #pragma unroll
        for (int r = 0; r < 4; ++r) lo[wid >> 1][lg * 4 + r][lq] = acc[r];
    }
    __syncthreads();
    if (!half) {
        const int n = row * 16 + lq;
        #pragma unroll
        for (int r = 0; r < 4; ++r) {
            const int co = co0 + lg * 4 + r;
            out[co * NVOX + n] = acc[r] + lo[wid >> 1][lg * 4 + r][lq] + bias[co];
        }
    }
}

extern "C" void kernel_launch(void* const* d_in, const int* in_sizes, int n_in,
                              void* d_out, int out_size, void* d_ws, size_t ws_size,
                              hipStream_t stream) {
    const float* x     = (const float*)d_in[0];
    const float* lw    = (const float*)d_in[1];
    const float* lb    = (const float*)d_in[2];
    const float* pos   = (const float*)d_in[3];
    const float* qw    = (const float*)d_in[4];
    const float* qb    = (const float*)d_in[5];
    const float* kw    = (const float*)d_in[6];
    const float* kb    = (const float*)d_in[7];
    const float* vw    = (const float*)d_in[8];
    const float* vb    = (const float*)d_in[9];
    const float* gamma = (const float*)d_in[10];
    const float* ow    = (const float*)d_in[11];
    const float* ob    = (const float*)d_in[12];

    float* latA  = (float*)d_ws;                 // 524288 f
    float* latB  = latA + 524288;                // 524288 f
    short* latbf = (short*)(latB + 524288);      // 524288 sh
    short* qB    = latbf + 524288;               // 524288 sh
    short* kB    = qB + 524288;                  // 524288 sh
    short* vT    = kB + 524288;                  // 524288 sh
    short* xpad  = vT + 524288;                  // 746496 sh (shared conv1/conv2)
    short* wbf1  = xpad + 746496;                // 221184 sh
    short* wqkv  = wbf1 + 221184;                // 442368 sh
    short* wbf2  = wqkv + 442368;                // 442368 sh

    pack_x   <<<1458, 256, 0, stream>>>(x, xpad);
    pack_w1  <<< 864, 256, 0, stream>>>(lw, wbf1);
    pack_wqkv<<< 576, 256, 0, stream>>>(qw, kw, vw, wqkv);
    pack_w2  <<<1728, 256, 0, stream>>>(ow, wbf2);

    conv1_mfma<<<1024, 256, 0, stream>>>(xpad, wbf1, lb, pos, latA, latbf);

    float* cur = latA;
    float* nxt = latB;
    for (int i = 0; i < 3; ++i) {
        proj_mfma<<<dim3(64, 8, 3), 256, 0, stream>>>(
            latbf, wqkv + i * 49152, qb + i * 128, kb + i * 128, vb + i * 128, qB, kB, vT);
        attn_kernel<<<1024, 256, 0, stream>>>(qB, kB, vT, cur, nxt, latbf, gamma, i);
        float* t = cur; cur = nxt; nxt = t;
    }

    pad2_kernel<<<365, 256, 0, stream>>>(latbf, xpad);
    conv2_mfma<<<1024, 256, 0, stream>>>(xpad, wbf2, ob, (float*)d_out);
}

// Round 5
// 206.394 us; speedup vs baseline: 16.4601x; 1.6554x over previous
//
#include <hip/hip_runtime.h>
#include <hip/hip_bf16.h>

#define NVOX 4096   // 16*16*16
#define CDIM 128

typedef __attribute__((ext_vector_type(8)))  short bf16x8;
typedef __attribute__((ext_vector_type(4)))  float f32x4;
typedef __attribute__((ext_vector_type(16))) float f32x16;

static __device__ __forceinline__ short f2bf(float f) {
    __hip_bfloat16 h = __float2bfloat16(f);
    union { __hip_bfloat16 h; short s; } u; u.h = h; return u.s;
}
static __device__ __forceinline__ float fexp2(float x) {
    return __builtin_amdgcn_exp2f(x);
}
// MFMA K-fragment permutation for K=128 staging: packed position p <- channel ci
__device__ __forceinline__ int permpos(int ci) {
    return (((ci >> 2) & 3) << 3) + (ci & 3) + ((ci & 16) >> 2) + ((ci >> 5) << 5);
}
__device__ __forceinline__ int invp(int p) {
    const int c = p >> 5, r = p & 31, g = (r >> 3) & 3, j = r & 7;
    return (c << 5) + (j < 4 ? (g << 2) + j : 16 + (g << 2) + (j - 4));
}
// 16-element fragment permutation for 32x32x16 (K=16): pos(d)
__device__ __forceinline__ int pos16(int d) {
    return (d & 3) | ((d & 4) << 1) | ((d & 8) >> 1);
}

// ---------------- prep kernels ----------------
__global__ __launch_bounds__(256) void pack_x(const float* __restrict__ x, short* __restrict__ xp) {
    const int e = blockIdx.x * 256 + threadIdx.x;
    if (e >= 5832 * 64) return;
    const int vp = e >> 6, p = e & 63;
    const int z = vp / 324, rem = vp - z * 324, y = rem / 18, xx = rem % 18;
    short val = 0;
    if (z >= 1 && z <= 16 && y >= 1 && y <= 16 && xx >= 1 && xx <= 16) {
        const int n = ((z - 1) * 16 + (y - 1)) * 16 + (xx - 1);
        val = f2bf(x[invp(p) * NVOX + n]);
    }
    xp[e] = val;
}

__global__ __launch_bounds__(256) void pack_w1(const float* __restrict__ lw, short* __restrict__ wb) {
    const int e = blockIdx.x * 256 + threadIdx.x;
    if (e >= 27 * 128 * 64) return;
    const int t = e >> 13, co = (e >> 6) & 127, p = e & 63;
    wb[e] = f2bf(lw[(co * 64 + invp(p)) * 27 + t]);
}

__global__ __launch_bounds__(256) void pack_wqkv(const float* __restrict__ qw, const float* __restrict__ kw,
                                                 const float* __restrict__ vw, short* __restrict__ wb) {
    const int e = blockIdx.x * 256 + threadIdx.x;
    if (e >= 3 * 3 * 128 * 128) return;
    const int l = e / 49152, r = e - l * 49152;
    const int m = r >> 14, co = (r >> 7) & 127, p = r & 127;
    const float* W = (m == 0 ? qw : m == 1 ? kw : vw) + l * 16384;
    wb[e] = f2bf(W[co * 128 + invp(p)]);
}

__global__ __launch_bounds__(256) void pack_w2(const float* __restrict__ ow, short* __restrict__ wb) {
    const int e = blockIdx.x * 256 + threadIdx.x;
    if (e >= 27 * 128 * 128) return;
    const int t = e >> 14, co = (e >> 7) & 127, p = e & 127;
    wb[e] = f2bf(ow[(invp(p) * 128 + co) * 27 + (26 - t)]);
}

__global__ __launch_bounds__(256) void pad2_kernel(const short* __restrict__ latbf, short* __restrict__ xp) {
    const int e = blockIdx.x * 256 + threadIdx.x;
    if (e >= 5832 * 16) return;
    const int vp = e >> 4, c8 = e & 15;
    const int z = vp / 324, rem = vp - z * 324, y = rem / 18, xx = rem % 18;
    int4 val = {0, 0, 0, 0};
    if (z >= 1 && z <= 16 && y >= 1 && y <= 16 && xx >= 1 && xx <= 16) {
        const int n = ((z - 1) * 16 + (y - 1)) * 16 + (xx - 1);
        val = *reinterpret_cast<const int4*>(latbf + n * 128 + c8 * 8);
    }
    *reinterpret_cast<int4*>(xp + vp * 128 + c8 * 8) = val;
}

// ---------------- conv1: MFMA over 27 taps, K=64 ----------------
__global__ __launch_bounds__(256) void conv1_mfma(
    const short* __restrict__ xp,   // [5832][64perm]
    const short* __restrict__ wb,   // [27][128][64perm]
    const float* __restrict__ bias, const float* __restrict__ pos,
    float* __restrict__ lat, short* __restrict__ latbf)
{
    __shared__ float lo[2][16][17];
    const int wid = threadIdx.x >> 6, lane = threadIdx.x & 63;
    const int lg = lane >> 4, lq = lane & 15;
    const int cot = blockIdx.x >> 7, rp = blockIdx.x & 127;
    const int row = rp * 2 + (wid >> 1);
    const int half = wid & 1;
    const int z = row >> 4, y = row & 15;
    const int co0 = cot * 16;

    const short* wbase = wb + (co0 + lq) * 64 + lg * 8;
    const short* xbase = xp + lq * 64 + lg * 8;

    f32x4 acc = {0.f, 0.f, 0.f, 0.f};
    const int t0 = half ? 14 : 0, t1 = half ? 27 : 14;
    for (int t = t0; t < t1; ++t) {
        const int dz = t / 9, r9 = t - dz * 9, dy = r9 / 3, dx = r9 - dy * 3;
        const int vp = ((z + dz) * 18 + (y + dy)) * 18 + dx;
        const short* wt = wbase + t * 8192;
        const short* xt = xbase + vp * 64;
        #pragma unroll
        for (int c = 0; c < 2; ++c) {
            const bf16x8 a = *reinterpret_cast<const bf16x8*>(wt + c * 32);
            const bf16x8 b = *reinterpret_cast<const bf16x8*>(xt + c * 32);
            acc = __builtin_amdgcn_mfma_f32_16x16x32_bf16(a, b, acc, 0, 0, 0);
        }
    }
    if (half) {
        #pragma unroll
        for (int r = 0; r < 4; ++r) lo[wid >> 1][lg * 4 + r][lq] = acc[r];
    }
    __syncthreads();
    if (!half) {
        const int n = row * 16 + lq;
        short4 s4;
        #pragma unroll
        for (int r = 0; r < 4; ++r) {
            const int co = co0 + lg * 4 + r;
            const float v = acc[r] + lo[wid >> 1][lg * 4 + r][lq] + bias[co] + pos[co * NVOX + n];
            lat[co * NVOX + n] = v;
            ((short*)&s4)[r] = f2bf(v);
        }
        const int pb = permpos(co0 + lg * 4);
        *reinterpret_cast<short4*>(latbf + n * 128 + pb) = s4;
    }
}

// ---------------- proj: 3x GEMM 128x4096x128, MFMA; outputs in 32x32x16 layouts ----------------
// qP/kP: [h][n][16] bf16, d stored at pos16(d); q pre-scaled by log2(e)/4
// vP:    [h][17][4096] bf16: rows 0..15 = V^T with per-16-key-group pos16 permutation; row 16 = ones
__global__ __launch_bounds__(256) void proj_mfma(
    const short* __restrict__ latbf,     // [4096][128perm]
    const short* __restrict__ wl,        // [3][128][128perm] (this layer)
    const float* __restrict__ bq, const float* __restrict__ bk, const float* __restrict__ bv,
    short* __restrict__ qP, short* __restrict__ kP, short* __restrict__ vP)
{
    const int m = blockIdx.z;
    const int wid = threadIdx.x >> 6, lane = threadIdx.x & 63;
    const int lg = lane >> 4, lq = lane & 15;
    const int co0 = blockIdx.y * 16;
    const int row = blockIdx.x * 4 + wid;
    const int n = row * 16 + lq;

    const short* A = wl + m * 16384 + (co0 + lq) * 128 + lg * 8;
    const short* B = latbf + n * 128 + lg * 8;

    f32x4 acc = {0.f, 0.f, 0.f, 0.f};
    #pragma unroll
    for (int c = 0; c < 4; ++c) {
        const bf16x8 a = *reinterpret_cast<const bf16x8*>(A + c * 32);
        const bf16x8 b = *reinterpret_cast<const bf16x8*>(B + c * 32);
        acc = __builtin_amdgcn_mfma_f32_16x16x32_bf16(a, b, acc, 0, 0, 0);
    }

    const int h = blockIdx.y;
    if (m == 2) {
        const float* bias = bv;
        const int col = row * 16 + pos16(lq);
        #pragma unroll
        for (int r = 0; r < 4; ++r) {
            const int d = lg * 4 + r;
            vP[(h * 17 + d) * NVOX + col] = f2bf(acc[r] + bias[co0 + d]);
        }
        if (lg == 0) vP[(h * 17 + 16) * NVOX + col] = (short)0x3F80;  // bf16 1.0
    } else {
        const float* bias = (m == 0) ? bq : bk;
        const float S = (m == 0) ? 0.25f * 1.4426950408889634f : 1.f;
        const int pg = ((lg & 1) << 3) | ((lg & 2) << 1);   // pos16(lg*4)
        short4 s4;
        #pragma unroll
        for (int r = 0; r < 4; ++r) {
            const int co = co0 + lg * 4 + r;
            ((short*)&s4)[r] = f2bf((acc[r] + bias[co]) * S);
        }
        short* dst = (m == 0) ? qP : kP;
        *reinterpret_cast<short4*>(dst + ((h << 12) + n) * 16 + pg) = s4;
    }
}

// ---------------- attn: 32x32x16 MFMA flash attention, no-max softmax ----------------
// Block = 4 waves; each wave: 32-query tile (blockIdx.x), 1024-key range (wid).
// S = mfma32x32x16(K,Q): lane holds S[key=(r&3)+8*(r>>2)+4*(l>>5)][q=l&31].
// P = exp2(S) in place; P^T regs feed O = mfma32x32x16(P^T, V) directly
// (A k-pattern == C row-pattern). vP row16=ones makes C col 16 = rowsum(P).
__global__ __launch_bounds__(256) void attn_mfma(
    const short* __restrict__ qP, const short* __restrict__ kP, const short* __restrict__ vP,
    const float* __restrict__ latin, float* __restrict__ latout, short* __restrict__ latbf,
    const float* __restrict__ gamma, int layer)
{
    __shared__ float smO[4][32][17];
    const int tid = threadIdx.x;
    const int wid = tid >> 6, lane = tid & 63;
    const int l5 = lane >> 5, lm = lane & 31;
    const int h = blockIdx.y;
    const int qbase = blockIdx.x * 32;

    const bf16x8 qf = *reinterpret_cast<const bf16x8*>(
        qP + (((h << 12) + qbase + lm) << 4) + l5 * 8);

    const short* kbase = kP + (((size_t)h) << 16);       // h*4096*16
    const int vrow = (lm & 16) ? 16 : lm;                // cols >16 -> ones row (ignored)
    const short* vbase = vP + ((size_t)h * 17 + vrow) * NVOX + l5 * 8;

    f32x16 acc = {0.f,0.f,0.f,0.f,0.f,0.f,0.f,0.f,0.f,0.f,0.f,0.f,0.f,0.f,0.f,0.f};
    const f32x16 zero = acc;

    int kc = wid * 1024;
    for (int it = 0; it < 32; ++it, kc += 32) {
        const bf16x8 kf = *reinterpret_cast<const bf16x8*>(kbase + ((kc + lm) << 4) + l5 * 8);
        const f32x16 S = __builtin_amdgcn_mfma_f32_32x32x16_bf16(kf, qf, zero, 0, 0, 0);

        short p[16];
        #pragma unroll
        for (int r = 0; r < 16; ++r) p[r] = f2bf(fexp2(S[r]));
        const bf16x8 pa0 = {p[0], p[1], p[2], p[3], p[4], p[5], p[6], p[7]};
        const bf16x8 pa1 = {p[8], p[9], p[10], p[11], p[12], p[13], p[14], p[15]};

        const bf16x8 vf0 = *reinterpret_cast<const bf16x8*>(vbase + kc);
        const bf16x8 vf1 = *reinterpret_cast<const bf16x8*>(vbase + kc + 16);

        acc = __builtin_amdgcn_mfma_f32_32x32x16_bf16(pa0, vf0, acc, 0, 0, 0);
        acc = __builtin_amdgcn_mfma_f32_32x32x16_bf16(pa1, vf1, acc, 0, 0, 0);
    }

    if (lm <= 16) {
        #pragma unroll
        for (int r = 0; r < 16; ++r) {
            const int qrow = (r & 3) + 8 * (r >> 2) + 4 * l5;
            smO[wid][qrow][lm] = acc[r];
        }
    }
    __syncthreads();

    // 256 threads finalize 32q x 16d: combine 4 k-splits, normalize, residual, dual write
    const int q = tid >> 3;
    const int d0 = (tid & 7) * 2;
    const float ls = smO[0][q][16] + smO[1][q][16] + smO[2][q][16] + smO[3][q][16];
    const float ginv = gamma[layer] / ls;
    const int n = qbase + q;
    #pragma unroll
    for (int dd = 0; dd < 2; ++dd) {
        const int d = d0 + dd;
        const float Ov = smO[0][q][d] + smO[1][q][d] + smO[2][q][d] + smO[3][q][d];
        const int c = (h << 4) + d;
        const float val = Ov * ginv + latin[c * NVOX + n];
        latout[c * NVOX + n] = val;
        latbf[n * 128 + permpos(c)] = f2bf(val);
    }
}

// ---------------- conv2: MFMA over 27 taps, K=128 ----------------
__global__ __launch_bounds__(256) void conv2_mfma(
    const short* __restrict__ xp,   // [5832][128perm]
    const short* __restrict__ wb,   // [27][128][128perm]
    const float* __restrict__ bias,
    float* __restrict__ out)
{
    __shared__ float lo[2][16][17];
    const int wid = threadIdx.x >> 6, lane = threadIdx.x & 63;
    const int lg = lane >> 4, lq = lane & 15;
    const int cot = blockIdx.x >> 7, rp = blockIdx.x & 127;
    const int row = rp * 2 + (wid >> 1);
    const int half = wid & 1;
    const int z = row >> 4, y = row & 15;
    const int co0 = cot * 16;

    const short* wbase = wb + (co0 + lq) * 128 + lg * 8;
    const short* xbase = xp + lq * 128 + lg * 8;

    f32x4 acc = {0.f, 0.f, 0.f, 0.f};
    const int t0 = half ? 14 : 0, t1 = half ? 27 : 14;
    for (int t = t0; t < t1; ++t) {
        const int dz = t / 9, r9 = t - dz * 9, dy = r9 / 3, dx = r9 - dy * 3;
        const int vp = ((z + dz) * 18 + (y + dy)) * 18 + dx;
        const short* wt = wbase + t * 16384;
        const short* xt = xbase + vp * 128;
        #pragma unroll
        for (int c = 0; c < 4; ++c) {
            const bf16x8 a = *reinterpret_cast<const bf16x8*>(wt + c * 32);
            const bf16x8 b = *reinterpret_cast<const bf16x8*>(xt + c * 32);
            acc = __builtin_amdgcn_mfma_f32_16x16x32_bf16(a, b, acc, 0, 0, 0);
        }
    }
    if (half) {
        #pragma unroll
        for (int r = 0; r < 4; ++r) lo[wid >> 1][lg * 4 + r][lq] = acc[r];
    }
    __syncthreads();
    if (!half) {
        const int n = row * 16 + lq;
        #pragma unroll
        for (int r = 0; r < 4; ++r) {
            const int co = co0 + lg * 4 + r;
            out[co * NVOX + n] = acc[r] + lo[wid >> 1][lg * 4 + r][lq] + bias[co];
        }
    }
}

extern "C" void kernel_launch(void* const* d_in, const int* in_sizes, int n_in,
                              void* d_out, int out_size, void* d_ws, size_t ws_size,
                              hipStream_t stream) {
    const float* x     = (const float*)d_in[0];
    const float* lw    = (const float*)d_in[1];
    const float* lb    = (const float*)d_in[2];
    const float* pos   = (const float*)d_in[3];
    const float* qw    = (const float*)d_in[4];
    const float* qb    = (const float*)d_in[5];
    const float* kw    = (const float*)d_in[6];
    const float* kb    = (const float*)d_in[7];
    const float* vw    = (const float*)d_in[8];
    const float* vb    = (const float*)d_in[9];
    const float* gamma = (const float*)d_in[10];
    const float* ow    = (const float*)d_in[11];
    const float* ob    = (const float*)d_in[12];

    float* latA  = (float*)d_ws;                 // 524288 f
    float* latB  = latA + 524288;                // 524288 f
    short* latbf = (short*)(latB + 524288);      // 524288 sh
    short* qP    = latbf + 524288;               // 524288 sh
    short* kP    = qP + 524288;                  // 524288 sh
    short* vP    = kP + 524288;                  // 557056 sh (8*17*4096)
    short* xpad  = vP + 557056;                  // 746496 sh
    short* wbf1  = xpad + 746496;                // 221184 sh
    short* wqkv  = wbf1 + 221184;                // 442368 sh
    short* wbf2  = wqkv + 442368;                // 442368 sh

    pack_x   <<<1458, 256, 0, stream>>>(x, xpad);
    pack_w1  <<< 864, 256, 0, stream>>>(lw, wbf1);
    pack_wqkv<<< 576, 256, 0, stream>>>(qw, kw, vw, wqkv);
    pack_w2  <<<1728, 256, 0, stream>>>(ow, wbf2);

    conv1_mfma<<<1024, 256, 0, stream>>>(xpad, wbf1, lb, pos, latA, latbf);

    float* cur = latA;
    float* nxt = latB;
    for (int i = 0; i < 3; ++i) {
        proj_mfma<<<dim3(64, 8, 3), 256, 0, stream>>>(
            latbf, wqkv + i * 49152, qb + i * 128, kb + i * 128, vb + i * 128, qP, kP, vP);
        attn_mfma<<<dim3(128, 8), 256, 0, stream>>>(qP, kP, vP, cur, nxt, latbf, gamma, i);
        float* t = cur; cur = nxt; nxt = t;
    }

    pad2_kernel<<<365, 256, 0, stream>>>(latbf, xpad);
    conv2_mfma<<<1024, 256, 0, stream>>>(xpad, wbf2, ob, (float*)d_out);
}